// Round 1
// 110.788 us; speedup vs baseline: 1.0284x; 1.0284x over previous
//
#include <hip/hip_runtime.h>
#include <stdint.h>

#define EPS 1e-5f
#define N_NODES 8192

typedef __attribute__((ext_vector_type(8))) short short8;
typedef __attribute__((ext_vector_type(4))) float floatx4;
typedef __attribute__((ext_vector_type(2))) float floatx2;

__device__ __forceinline__ unsigned short f2bf(float f) {
    uint32_t u = __float_as_uint(f);
    u += 0x7FFFu + ((u >> 16) & 1u);
    return (unsigned short)(u >> 16);
}

// ---------------- K0 (tiny): W1 -> bf16 transposed, zero BN stat banks ----------------
__global__ __launch_bounds__(256) void prep_kernel(
    const float* __restrict__ W1, unsigned short* __restrict__ w1t,
    float* __restrict__ stat_ws)
{
    const int b2 = blockIdx.x, tid = threadIdx.x;   // 16 blocks
    const int n = b2 * 8 + (tid >> 5);              // 0..127 (output row of W1^T)
    const int k = (tid & 31) * 4;
#pragma unroll
    for (int e = 0; e < 4; ++e)
        w1t[n * 128 + k + e] = f2bf(W1[(k + e) * 128 + n]);
    if (b2 == 0) {
        floatx4 z = {0.f, 0.f, 0.f, 0.f};
        *(floatx4*)(stat_ws + tid * 4) = z;
    }
}

// ---------------- K1 (fused): blocks 0..127 GEMM y=x@W1 ; blocks 128..639 p2 + BN stats
// GEMM: 128 blocks x 4 waves, each wave 16 rows; x converted fp32->bf16 inline.
// p2:   512 blocks = 64 clouds x 8 splits; 16 i's per thread over a 64-j half.
//       p2 depends only on xyz/W_xyz, so it overlaps the MFMA blocks (VALU vs MFMA pipes).
__global__ __launch_bounds__(256, 4) void fused_gemm_p2_kernel(
    const float* __restrict__ x, const float* __restrict__ xyz,
    const float* __restrict__ W_xyz, const unsigned short* __restrict__ w1t,
    float* __restrict__ y_ws, float* __restrict__ p2_ws, float* __restrict__ stat_ws)
{
    __shared__ float s_xyz[512];    // [128][4] (p2 blocks only)
    __shared__ float s_red[2048];   // [16 i][128 d] h=1 partials (p2 blocks only)
    const int tid = threadIdx.x;

    if (blockIdx.x < 128) {
        // ---- GEMM part ----
        const int w = tid >> 6, lane = tid & 63;
        const int ml = lane & 15, q = lane >> 4;
        const int rbw = blockIdx.x * 64 + w * 16;

        short8 afrag[4];    // A[m=ml][k=32c+8q+e]
#pragma unroll
        for (int c = 0; c < 4; ++c) {
            const float* px = x + (rbw + ml) * 128 + c * 32 + q * 8;
            floatx4 v0 = *(const floatx4*)px;
            floatx4 v1 = *(const floatx4*)(px + 4);
            short8 a;
            a[0] = (short)f2bf(v0[0]); a[1] = (short)f2bf(v0[1]);
            a[2] = (short)f2bf(v0[2]); a[3] = (short)f2bf(v0[3]);
            a[4] = (short)f2bf(v1[0]); a[5] = (short)f2bf(v1[1]);
            a[6] = (short)f2bf(v1[2]); a[7] = (short)f2bf(v1[3]);
            afrag[c] = a;
        }
#pragma unroll
        for (int nt = 0; nt < 8; ++nt) {
            floatx4 acc = {0.f, 0.f, 0.f, 0.f};
            const int ncol = nt * 16 + ml;
#pragma unroll
            for (int c = 0; c < 4; ++c) {
                short8 b = *(const short8*)(w1t + ncol * 128 + c * 32 + q * 8);
                acc = __builtin_amdgcn_mfma_f32_16x16x32_bf16(afrag[c], b, acc, 0, 0, 0);
            }
#pragma unroll
            for (int r = 0; r < 4; ++r)
                y_ws[(rbw + q * 4 + r) * 128 + ncol] = acc[r];   // D: row=4q+r, col=ml
        }
    } else {
        // ---- p2 part ----
        const int bb = blockIdx.x - 128;
        const int c = bb >> 3, s = bb & 7;
        const int d = tid & 127, h = tid >> 7;
        const int node0 = c * 128, i0 = s * 16;

        if (tid < 128) {
            const float* p = xyz + (node0 + tid) * 3;
            s_xyz[tid * 4 + 0] = p[0];
            s_xyz[tid * 4 + 1] = p[1];
            s_xyz[tid * 4 + 2] = p[2];
            s_xyz[tid * 4 + 3] = 0.f;
        }
        __syncthreads();

        const float w0 = W_xyz[d], w1c = W_xyz[128 + d], w2c = W_xyz[256 + d];
        const floatx2 zv2 = {0.f, 0.f};
        floatx2 zi[8], a2[8];
#pragma unroll
        for (int r = 0; r < 16; ++r) {
            const int ia = i0 + r;
            zi[r >> 1][r & 1] = s_xyz[ia * 4] * w0 + s_xyz[ia * 4 + 1] * w1c
                              + s_xyz[ia * 4 + 2] * w2c;
            a2[r >> 1][r & 1] = 0.f;
        }
        const float* xp = s_xyz + h * 256;
#pragma unroll 4
        for (int j = 0; j < 64; ++j) {
            floatx4 xj = *(const floatx4*)(xp + j * 4);   // broadcast read
            const float zj = xj[0] * w0 + xj[1] * w1c + xj[2] * w2c;
            const floatx2 zj2 = {zj, zj};
#pragma unroll
            for (int r = 0; r < 8; ++r)
                a2[r] += __builtin_elementwise_max(zi[r] - zj2, zv2);
        }
        // j==i self term: relu(zi-zi)=0, no correction needed
        if (h == 1) {
#pragma unroll
            for (int r = 0; r < 16; ++r) s_red[r * 128 + d] = a2[r >> 1][r & 1];
        }
        __syncthreads();
        if (h == 0) {
            float bs = 0.f, bq = 0.f;
#pragma unroll
            for (int r = 0; r < 16; ++r) {
                const float v2 = a2[r >> 1][r & 1] + s_red[r * 128 + d];
                p2_ws[(node0 + i0 + r) * 128 + d] = v2;
                bs += v2;
                bq += v2 * v2;
            }
            const int bank = (bb & 3) * 256;
            atomicAdd(stat_ws + bank + d,       bs);
            atomicAdd(stat_ws + bank + 128 + d, bq);
        }
    }
}

// ---------------- K2: a1 loop + LN + BN apply -> single out store ----------------
// grid = 1024: c = bx&63, s = bx>>6 (16 splits); 8 i's per thread over a 64-j half.
__global__ __launch_bounds__(256, 4) void cloud_main_kernel(
    const float* __restrict__ x, const float* __restrict__ xyz,
    const float* __restrict__ b1, const float* __restrict__ ln_gamma,
    const float* __restrict__ ln_beta, const float* __restrict__ bn_gamma,
    const float* __restrict__ bn_beta, const float* __restrict__ y_ws,
    const float* __restrict__ p2_ws, const float* __restrict__ stat_ws,
    float* __restrict__ out)
{
    __shared__ float s_xyz[512];    // [128][4]
    __shared__ float s_w[1024];     // [128 j][8 i]
    __shared__ float s_red[1024];   // h=1 a1 partials [8][128]
    __shared__ float s_p1[1088];    // [8][136] merged p1 for LN reduce
    __shared__ float s_mu[8];
    __shared__ float s_rs[8];
    __shared__ float s_A[128];      // BN scale
    __shared__ float s_B[128];      // BN shift

    const int bx = blockIdx.x;
    const int c = bx & 63, s = bx >> 6;
    const int tid = threadIdx.x;
    const int d = tid & 127, h = tid >> 7;
    const int node0 = c * 128;
    const int i0 = s * 8;

    if (tid < 128) {
        const float* p = xyz + (node0 + tid) * 3;
        s_xyz[tid * 4 + 0] = p[0];
        s_xyz[tid * 4 + 1] = p[1];
        s_xyz[tid * 4 + 2] = p[2];
        s_xyz[tid * 4 + 3] = 0.f;
        // BN affine coefficients from global stats (K1 complete by stream order)
        float sm = 0.f, sq = 0.f;
#pragma unroll
        for (int b = 0; b < 4; ++b) {
            sm += stat_ws[b * 256 + tid];
            sq += stat_ws[b * 256 + 128 + tid];
        }
        const float mu = sm * (1.f / 8192.f);
        const float var = sq * (1.f / 8192.f) - mu * mu;
        const float A = rsqrtf(var + EPS) * bn_gamma[tid];
        s_A[tid] = A;
        s_B[tid] = bn_beta[tid] - mu * A;
    }
    __syncthreads();

    // w tile: w[j][ii] = exp(-|xyz_{i0+ii} - xyz_j|)
    for (int e = tid; e < 1024; e += 256) {
        const int j = e >> 3, ii = e & 7, ia = i0 + ii;
        float dx = s_xyz[ia * 4]     - s_xyz[j * 4];
        float dy = s_xyz[ia * 4 + 1] - s_xyz[j * 4 + 1];
        float dz = s_xyz[ia * 4 + 2] - s_xyz[j * 4 + 2];
        s_w[j * 8 + ii] = __expf(-sqrtf(dx * dx + dy * dy + dz * dz));
    }
    __syncthreads();

    const float b1d = b1[d];
    const floatx2 b1v = {b1d, b1d};
    const floatx2 zv2 = {0.f, 0.f};

    floatx2 yi[4], a1[4];
#pragma unroll
    for (int r = 0; r < 8; ++r) {
        yi[r >> 1][r & 1] = y_ws[(node0 + i0 + r) * 128 + d];
        a1[r >> 1][r & 1] = 0.f;
    }

    const float* yrow = y_ws + (node0 + h * 64) * 128 + d;
    const float* wp = s_w + h * 512;

#pragma unroll 4
    for (int j = 0; j < 64; ++j) {
        const float yj = yrow[j * 128];
        floatx4 wa = *(const floatx4*)(wp + j * 8);       // broadcast
        floatx4 wb = *(const floatx4*)(wp + j * 8 + 4);   // broadcast
        const floatx2 yj2 = {yj, yj};
        floatx2 wlo = {wa[0], wa[1]}, wmd = {wa[2], wa[3]};
        floatx2 wh0 = {wb[0], wb[1]}, wh1 = {wb[2], wb[3]};
        a1[0] += __builtin_elementwise_max(wlo * (yi[0] - yj2) + b1v, zv2);
        a1[1] += __builtin_elementwise_max(wmd * (yi[1] - yj2) + b1v, zv2);
        a1[2] += __builtin_elementwise_max(wh0 * (yi[2] - yj2) + b1v, zv2);
        a1[3] += __builtin_elementwise_max(wh1 * (yi[3] - yj2) + b1v, zv2);
    }

    // h=1 publishes partials
    if (h == 1) {
#pragma unroll
        for (int r = 0; r < 8; ++r) s_red[r * 128 + d] = a1[r >> 1][r & 1];
    }
    __syncthreads();

    // h=0 merges; self term j==i contributes relu(b1d)
    if (h == 0) {
        const float selfc = fmaxf(b1d, 0.f);
#pragma unroll
        for (int r = 0; r < 8; ++r) {
            const float v1 = a1[r >> 1][r & 1] + s_red[r * 128 + d] - selfc;
            a1[r >> 1][r & 1] = v1;
            s_p1[r * 136 + d] = v1;
        }
    }
    __syncthreads();

    // LN stats: 32 threads per i, 4 d's each, shuffle reduce
    {
        const int ii = tid >> 5, sub = tid & 31;
        floatx4 v = *(const floatx4*)(s_p1 + ii * 136 + sub * 4);
        float ps = v[0] + v[1] + v[2] + v[3];
        float pq = v[0] * v[0] + v[1] * v[1] + v[2] * v[2] + v[3] * v[3];
#pragma unroll
        for (int m = 1; m < 32; m <<= 1) {
            ps += __shfl_xor(ps, m, 64);
            pq += __shfl_xor(pq, m, 64);
        }
        if (sub == 0) {
            const float mu = ps * (1.f / 128.f);
            const float var = pq * (1.f / 128.f) - mu * mu;
            s_mu[ii] = mu;
            s_rs[ii] = rsqrtf(var + EPS);
        }
    }
    __syncthreads();

    // epilogue: out = x + LN(p1)*lng + lnb + p2*A + B  (single store)
    if (h == 0) {
        const float lng = ln_gamma[d], lnb = ln_beta[d];
        const float A = s_A[d], B = s_B[d];
#pragma unroll
        for (int r = 0; r < 8; ++r) {
            const int gi = node0 + i0 + r;
            out[gi * 128 + d] = x[gi * 128 + d]
                + (a1[r >> 1][r & 1] - s_mu[r]) * s_rs[r] * lng + lnb
                + p2_ws[gi * 128 + d] * A + B;
        }
    }
}

extern "C" void kernel_launch(void* const* d_in, const int* in_sizes, int n_in,
                              void* d_out, int out_size, void* d_ws, size_t ws_size,
                              hipStream_t stream) {
    const float* x        = (const float*)d_in[0];
    const float* xyz      = (const float*)d_in[1];
    const float* W_xyz    = (const float*)d_in[2];
    const float* bn_gamma = (const float*)d_in[3];
    const float* bn_beta  = (const float*)d_in[4];
    const float* W1       = (const float*)d_in[5];
    const float* b1       = (const float*)d_in[6];
    const float* ln_gamma = (const float*)d_in[7];
    const float* ln_beta  = (const float*)d_in[8];
    float* out = (float*)d_out;

    float* y_ws    = (float*)d_ws;                       // [8192][128] fp32, 4 MB
    float* p2_ws   = y_ws + N_NODES * 128;               // [8192][128] fp32, 4 MB
    float* stat_ws = p2_ws + N_NODES * 128;              // 4 banks x (sum[128], sumsq[128])
    unsigned short* w1t = (unsigned short*)(stat_ws + 1024);  // [128][128] bf16 transposed

    prep_kernel<<<16, 256, 0, stream>>>(W1, w1t, stat_ws);
    fused_gemm_p2_kernel<<<640, 256, 0, stream>>>(x, xyz, W_xyz, w1t, y_ws, p2_ws, stat_ws);
    cloud_main_kernel<<<1024, 256, 0, stream>>>(x, xyz, b1, ln_gamma, ln_beta,
                                                bn_gamma, bn_beta, y_ws, p2_ws,
                                                stat_ws, out);
}

// Round 2
// 110.489 us; speedup vs baseline: 1.0312x; 1.0027x over previous
//
#include <hip/hip_runtime.h>
#include <stdint.h>

#define EPS 1e-5f
#define N_NODES 8192

typedef __attribute__((ext_vector_type(8))) short short8;
typedef __attribute__((ext_vector_type(4))) float floatx4;
typedef __attribute__((ext_vector_type(2))) float floatx2;

__device__ __forceinline__ unsigned short f2bf(float f) {
    uint32_t u = __float_as_uint(f);
    u += 0x7FFFu + ((u >> 16) & 1u);
    return (unsigned short)(u >> 16);
}

// ---------------- K1 (fused): blocks 0..127 GEMM y=x@W1 ; blocks 128..639 p2 + BN stats
// GEMM: 128 blocks x 4 waves, each wave 16 rows; x converted fp32->bf16 inline;
//       W1 converted+transposed to LDS per block (64KB L2-hit read, hidden under p2 blocks).
// p2:   512 blocks = 64 clouds x 8 splits; 16 i's per thread over a 64-j half.
//       p2 depends only on xyz/W_xyz, so it overlaps the MFMA blocks (VALU vs MFMA pipes).
__global__ __launch_bounds__(256, 4) void fused_gemm_p2_kernel(
    const float* __restrict__ x, const float* __restrict__ xyz,
    const float* __restrict__ W_xyz, const float* __restrict__ W1,
    float* __restrict__ y_ws, float* __restrict__ p2_ws, float* __restrict__ stat_ws)
{
    // union: GEMM uses bf16 W1^T [128 n][136 k-stride]; p2 uses s_xyz(2KB)+s_red(8KB)
    __shared__ __align__(16) unsigned char s_mem[128 * 136 * 2];
    const int tid = threadIdx.x;

    if (blockIdx.x < 128) {
        // ---- GEMM part ----
        unsigned short* s_w1t = (unsigned short*)s_mem;

        // W1 [k][n] fp32 -> LDS bf16 transposed [n][k], row stride 136 halves.
        // thread: n = tid>>1, k in [kh, kh+64); reads column n coalesced in 128B
        // half-wave segments, writes packed b32 pairs.
        {
            const int n = tid >> 1;
            const int kh = (tid & 1) * 64;
            unsigned short* row = s_w1t + n * 136 + kh;
#pragma unroll
            for (int j = 0; j < 32; ++j) {
                float a = W1[(kh + 2 * j) * 128 + n];
                float b = W1[(kh + 2 * j + 1) * 128 + n];
                uint32_t pk = (uint32_t)f2bf(a) | ((uint32_t)f2bf(b) << 16);
                *(uint32_t*)(row + 2 * j) = pk;
            }
        }

        const int w = tid >> 6, lane = tid & 63;
        const int ml = lane & 15, q = lane >> 4;
        const int rbw = blockIdx.x * 64 + w * 16;

        short8 afrag[4];    // A[m=ml][k=32c+8q+e]
#pragma unroll
        for (int c = 0; c < 4; ++c) {
            const float* px = x + (rbw + ml) * 128 + c * 32 + q * 8;
            floatx4 v0 = *(const floatx4*)px;
            floatx4 v1 = *(const floatx4*)(px + 4);
            short8 a;
            a[0] = (short)f2bf(v0[0]); a[1] = (short)f2bf(v0[1]);
            a[2] = (short)f2bf(v0[2]); a[3] = (short)f2bf(v0[3]);
            a[4] = (short)f2bf(v1[0]); a[5] = (short)f2bf(v1[1]);
            a[6] = (short)f2bf(v1[2]); a[7] = (short)f2bf(v1[3]);
            afrag[c] = a;
        }
        __syncthreads();   // W1^T tile ready

#pragma unroll
        for (int nt = 0; nt < 8; ++nt) {
            floatx4 acc = {0.f, 0.f, 0.f, 0.f};
            const int ncol = nt * 16 + ml;
#pragma unroll
            for (int c = 0; c < 4; ++c) {
                short8 b = *(const short8*)(s_w1t + ncol * 136 + c * 32 + q * 8);
                acc = __builtin_amdgcn_mfma_f32_16x16x32_bf16(afrag[c], b, acc, 0, 0, 0);
            }
#pragma unroll
            for (int r = 0; r < 4; ++r)
                y_ws[(rbw + q * 4 + r) * 128 + ncol] = acc[r];   // D: row=4q+r, col=ml
        }
    } else {
        // ---- p2 part ----
        float* s_xyz = (float*)s_mem;             // [128][4]
        float* s_red = (float*)(s_mem + 2048);    // [16 i][128 d]

        const int bb = blockIdx.x - 128;
        const int c = bb >> 3, s = bb & 7;
        const int d = tid & 127, h = tid >> 7;
        const int node0 = c * 128, i0 = s * 16;

        if (tid < 128) {
            const float* p = xyz + (node0 + tid) * 3;
            s_xyz[tid * 4 + 0] = p[0];
            s_xyz[tid * 4 + 1] = p[1];
            s_xyz[tid * 4 + 2] = p[2];
            s_xyz[tid * 4 + 3] = 0.f;
        }
        __syncthreads();

        const float w0 = W_xyz[d], w1c = W_xyz[128 + d], w2c = W_xyz[256 + d];
        const floatx2 zv2 = {0.f, 0.f};
        floatx2 zi[8], a2[8];
#pragma unroll
        for (int r = 0; r < 16; ++r) {
            const int ia = i0 + r;
            zi[r >> 1][r & 1] = s_xyz[ia * 4] * w0 + s_xyz[ia * 4 + 1] * w1c
                              + s_xyz[ia * 4 + 2] * w2c;
            a2[r >> 1][r & 1] = 0.f;
        }
        const float* xp = s_xyz + h * 256;
#pragma unroll 4
        for (int j = 0; j < 64; ++j) {
            floatx4 xj = *(const floatx4*)(xp + j * 4);   // broadcast read
            const float zj = xj[0] * w0 + xj[1] * w1c + xj[2] * w2c;
            const floatx2 zj2 = {zj, zj};
#pragma unroll
            for (int r = 0; r < 8; ++r)
                a2[r] += __builtin_elementwise_max(zi[r] - zj2, zv2);
        }
        // j==i self term: relu(zi-zi)=0, no correction needed
        if (h == 1) {
#pragma unroll
            for (int r = 0; r < 16; ++r) s_red[r * 128 + d] = a2[r >> 1][r & 1];
        }
        __syncthreads();
        if (h == 0) {
            float bs = 0.f, bq = 0.f;
#pragma unroll
            for (int r = 0; r < 16; ++r) {
                const float v2 = a2[r >> 1][r & 1] + s_red[r * 128 + d];
                p2_ws[(node0 + i0 + r) * 128 + d] = v2;
                bs += v2;
                bq += v2 * v2;
            }
            const int bank = (bb & 3) * 256;
            atomicAdd(stat_ws + bank + d,       bs);
            atomicAdd(stat_ws + bank + 128 + d, bq);
        }
    }
}

// ---------------- K2: a1 loop + LN + BN apply -> single out store ----------------
// grid = 1024: c = bx&63, s = bx>>6 (16 splits); 8 i's per thread over a 64-j half.
__global__ __launch_bounds__(256, 4) void cloud_main_kernel(
    const float* __restrict__ x, const float* __restrict__ xyz,
    const float* __restrict__ b1, const float* __restrict__ ln_gamma,
    const float* __restrict__ ln_beta, const float* __restrict__ bn_gamma,
    const float* __restrict__ bn_beta, const float* __restrict__ y_ws,
    const float* __restrict__ p2_ws, const float* __restrict__ stat_ws,
    float* __restrict__ out)
{
    __shared__ float s_xyz[512];    // [128][4]
    __shared__ float s_w[1024];     // [128 j][8 i]
    __shared__ float s_red[1024];   // h=1 a1 partials [8][128]
    __shared__ float s_p1[1088];    // [8][136] merged p1 for LN reduce
    __shared__ float s_mu[8];
    __shared__ float s_rs[8];
    __shared__ float s_A[128];      // BN scale
    __shared__ float s_B[128];      // BN shift

    const int bx = blockIdx.x;
    const int c = bx & 63, s = bx >> 6;
    const int tid = threadIdx.x;
    const int d = tid & 127, h = tid >> 7;
    const int node0 = c * 128;
    const int i0 = s * 8;

    if (tid < 128) {
        const float* p = xyz + (node0 + tid) * 3;
        s_xyz[tid * 4 + 0] = p[0];
        s_xyz[tid * 4 + 1] = p[1];
        s_xyz[tid * 4 + 2] = p[2];
        s_xyz[tid * 4 + 3] = 0.f;
        // BN affine coefficients from global stats (K1 complete by stream order)
        float sm = 0.f, sq = 0.f;
#pragma unroll
        for (int b = 0; b < 4; ++b) {
            sm += stat_ws[b * 256 + tid];
            sq += stat_ws[b * 256 + 128 + tid];
        }
        const float mu = sm * (1.f / 8192.f);
        const float var = sq * (1.f / 8192.f) - mu * mu;
        const float A = rsqrtf(var + EPS) * bn_gamma[tid];
        s_A[tid] = A;
        s_B[tid] = bn_beta[tid] - mu * A;
    }
    __syncthreads();

    // w tile: w[j][ii] = exp(-|xyz_{i0+ii} - xyz_j|)
    for (int e = tid; e < 1024; e += 256) {
        const int j = e >> 3, ii = e & 7, ia = i0 + ii;
        float dx = s_xyz[ia * 4]     - s_xyz[j * 4];
        float dy = s_xyz[ia * 4 + 1] - s_xyz[j * 4 + 1];
        float dz = s_xyz[ia * 4 + 2] - s_xyz[j * 4 + 2];
        s_w[j * 8 + ii] = __expf(-sqrtf(dx * dx + dy * dy + dz * dz));
    }
    __syncthreads();

    const float b1d = b1[d];
    const floatx2 b1v = {b1d, b1d};
    const floatx2 zv2 = {0.f, 0.f};

    floatx2 yi[4], a1[4];
#pragma unroll
    for (int r = 0; r < 8; ++r) {
        yi[r >> 1][r & 1] = y_ws[(node0 + i0 + r) * 128 + d];
        a1[r >> 1][r & 1] = 0.f;
    }

    const float* yrow = y_ws + (node0 + h * 64) * 128 + d;
    const float* wp = s_w + h * 512;

#pragma unroll 4
    for (int j = 0; j < 64; ++j) {
        const float yj = yrow[j * 128];
        floatx4 wa = *(const floatx4*)(wp + j * 8);       // broadcast
        floatx4 wb = *(const floatx4*)(wp + j * 8 + 4);   // broadcast
        const floatx2 yj2 = {yj, yj};
        floatx2 wlo = {wa[0], wa[1]}, wmd = {wa[2], wa[3]};
        floatx2 wh0 = {wb[0], wb[1]}, wh1 = {wb[2], wb[3]};
        a1[0] += __builtin_elementwise_max(wlo * (yi[0] - yj2) + b1v, zv2);
        a1[1] += __builtin_elementwise_max(wmd * (yi[1] - yj2) + b1v, zv2);
        a1[2] += __builtin_elementwise_max(wh0 * (yi[2] - yj2) + b1v, zv2);
        a1[3] += __builtin_elementwise_max(wh1 * (yi[3] - yj2) + b1v, zv2);
    }

    // h=1 publishes partials
    if (h == 1) {
#pragma unroll
        for (int r = 0; r < 8; ++r) s_red[r * 128 + d] = a1[r >> 1][r & 1];
    }
    __syncthreads();

    // h=0 merges; self term j==i contributes relu(b1d)
    if (h == 0) {
        const float selfc = fmaxf(b1d, 0.f);
#pragma unroll
        for (int r = 0; r < 8; ++r) {
            const float v1 = a1[r >> 1][r & 1] + s_red[r * 128 + d] - selfc;
            a1[r >> 1][r & 1] = v1;
            s_p1[r * 136 + d] = v1;
        }
    }
    __syncthreads();

    // LN stats: 32 threads per i, 4 d's each, shuffle reduce
    {
        const int ii = tid >> 5, sub = tid & 31;
        floatx4 v = *(const floatx4*)(s_p1 + ii * 136 + sub * 4);
        float ps = v[0] + v[1] + v[2] + v[3];
        float pq = v[0] * v[0] + v[1] * v[1] + v[2] * v[2] + v[3] * v[3];
#pragma unroll
        for (int m = 1; m < 32; m <<= 1) {
            ps += __shfl_xor(ps, m, 64);
            pq += __shfl_xor(pq, m, 64);
        }
        if (sub == 0) {
            const float mu = ps * (1.f / 128.f);
            const float var = pq * (1.f / 128.f) - mu * mu;
            s_mu[ii] = mu;
            s_rs[ii] = rsqrtf(var + EPS);
        }
    }
    __syncthreads();

    // epilogue: out = x + LN(p1)*lng + lnb + p2*A + B  (single store)
    if (h == 0) {
        const float lng = ln_gamma[d], lnb = ln_beta[d];
        const float A = s_A[d], B = s_B[d];
#pragma unroll
        for (int r = 0; r < 8; ++r) {
            const int gi = node0 + i0 + r;
            out[gi * 128 + d] = x[gi * 128 + d]
                + (a1[r >> 1][r & 1] - s_mu[r]) * s_rs[r] * lng + lnb
                + p2_ws[gi * 128 + d] * A + B;
        }
    }
}

extern "C" void kernel_launch(void* const* d_in, const int* in_sizes, int n_in,
                              void* d_out, int out_size, void* d_ws, size_t ws_size,
                              hipStream_t stream) {
    const float* x        = (const float*)d_in[0];
    const float* xyz      = (const float*)d_in[1];
    const float* W_xyz    = (const float*)d_in[2];
    const float* bn_gamma = (const float*)d_in[3];
    const float* bn_beta  = (const float*)d_in[4];
    const float* W1       = (const float*)d_in[5];
    const float* b1       = (const float*)d_in[6];
    const float* ln_gamma = (const float*)d_in[7];
    const float* ln_beta  = (const float*)d_in[8];
    float* out = (float*)d_out;

    float* y_ws    = (float*)d_ws;                       // [8192][128] fp32, 4 MB
    float* p2_ws   = y_ws + N_NODES * 128;               // [8192][128] fp32, 4 MB
    float* stat_ws = p2_ws + N_NODES * 128;              // 4 banks x (sum[128], sumsq[128])

    hipMemsetAsync(stat_ws, 0, 1024 * sizeof(float), stream);
    fused_gemm_p2_kernel<<<640, 256, 0, stream>>>(x, xyz, W_xyz, W1, y_ws, p2_ws, stat_ws);
    cloud_main_kernel<<<1024, 256, 0, stream>>>(x, xyz, b1, ln_gamma, ln_beta,
                                                bn_gamma, bn_beta, y_ws, p2_ws,
                                                stat_ws, out);
}